// Round 7
// baseline (246.154 us; speedup 1.0000x reference)
//
#include <hip/hip_runtime.h>
#include <stdint.h>

// B=4, T=1024, DIN=512, DLIN=1024, DK=DV=1024, NH=16, dk=dv=64
// h = data @ W_in[:, :512]^T + W_in[:, 512+t]   (identity concat == column bias)
// q/k/v = h @ W^T ; per-head attention, no max-subtract needed (logits ~ +-0.5).
// Q pre-scaled by 0.125*log2(e) in the QKV GEMM epilogue -> softmax is bare exp2.
// V^T stored sigma-permuted within 32-kv blocks so the PV A-fragment is a
// single 16B load per lane and P feeds the B-operand in register order.

typedef __bf16 bf16x8 __attribute__((ext_vector_type(8)));
typedef float f32x4 __attribute__((ext_vector_type(4)));
typedef unsigned short u16;
typedef u16 u16x8 __attribute__((ext_vector_type(8)));

#define MFMA16(a, b, c) __builtin_amdgcn_mfma_f32_16x16x32_bf16(a, b, c, 0, 0, 0)

using gld_src_t = const __attribute__((address_space(1))) unsigned int*;
using gld_dst_t = __attribute__((address_space(3))) unsigned int*;

__device__ __forceinline__ u16 f2bf(float f) {
  uint32_t u = __builtin_bit_cast(uint32_t, f);
  uint32_t r = (u + 0x7fffu + ((u >> 16) & 1u)) >> 16;
  return (u16)r;
}

// ---------------- conversions ----------------

__global__ __launch_bounds__(256) void cvt_all(
    const float* __restrict__ data, const float* __restrict__ wq,
    const float* __restrict__ wk, const float* __restrict__ wv,
    u16* __restrict__ o_data, u16* __restrict__ o_wq,
    u16* __restrict__ o_wk, u16* __restrict__ o_wv) {
  const float* s;
  u16* o;
  int n;
  switch (blockIdx.y) {
    case 0: s = data; o = o_data; n = 4096 * 512; break;
    case 1: s = wq; o = o_wq; n = 1024 * 1024; break;
    case 2: s = wk; o = o_wk; n = 1024 * 1024; break;
    default: s = wv; o = o_wv; n = 1024 * 1024; break;
  }
  int i = (blockIdx.x * 256 + threadIdx.x) * 8;
  if (i >= n) return;
  float4 a = *(const float4*)(s + i);
  float4 b = *(const float4*)(s + i + 4);
  u16x8 v;
  v[0] = f2bf(a.x); v[1] = f2bf(a.y); v[2] = f2bf(a.z); v[3] = f2bf(a.w);
  v[4] = f2bf(b.x); v[5] = f2bf(b.y); v[6] = f2bf(b.z); v[7] = f2bf(b.w);
  *(u16x8*)(o + i) = v;
}

__global__ __launch_bounds__(256) void cvt_win(const float* __restrict__ Win,
                                               u16* __restrict__ wd) {
  int i = (blockIdx.x * 256 + threadIdx.x) * 8;  // over 1024*512
  if (i >= 1024 * 512) return;
  int row = i >> 9, col = i & 511;
  const float* s = Win + (size_t)row * 1536 + col;
  float4 a = *(const float4*)s;
  float4 b = *(const float4*)(s + 4);
  u16x8 v;
  v[0] = f2bf(a.x); v[1] = f2bf(a.y); v[2] = f2bf(a.z); v[3] = f2bf(a.w);
  v[4] = f2bf(b.x); v[5] = f2bf(b.y); v[6] = f2bf(b.z); v[7] = f2bf(b.w);
  *(u16x8*)(wd + i) = v;
}

// ---------------- GEMM: C[4096,1024] = A[4096,K] @ Bw[1024,K]^T ----------------

template <int EPI>
__global__ __launch_bounds__(256) void gemm_bt(
    const u16* __restrict__ A, const u16* __restrict__ B0,
    const u16* __restrict__ B1, const u16* __restrict__ B2,
    const float* __restrict__ Wpos, u16* __restrict__ O0,
    u16* __restrict__ O1, u16* __restrict__ O2, int K) {
  __shared__ u16 Ash[128 * 64];
  __shared__ u16 Bsh[128 * 64];
  const int tid = threadIdx.x;
  const int lane = tid & 63;
  const int w = tid >> 6;
  const int wr = w >> 1, wc = w & 1;
  const int m0 = blockIdx.x * 128, n0 = blockIdx.y * 128;

  const u16* Bw;
  u16* Out;
  if constexpr (EPI == 0) {
    Bw = B0; Out = O0;
  } else {
    int z = blockIdx.z;
    Bw = (z == 0) ? B0 : (z == 1) ? B1 : B2;
    Out = (z == 0) ? O0 : (z == 1) ? O1 : O2;
  }

  f32x4 acc[4][4];
#pragma unroll
  for (int m = 0; m < 4; ++m)
#pragma unroll
    for (int n = 0; n < 4; ++n) acc[m][n] = (f32x4){0.f, 0.f, 0.f, 0.f};

  for (int kt = 0; kt < K; kt += 64) {
    __syncthreads();
#pragma unroll
    for (int i = 0; i < 4; ++i) {
      int c = i * 256 + tid;
      int row = c >> 3;
      int sg = (c & 7) ^ (row & 7);
      const u16* srcA = A + (size_t)(m0 + row) * K + kt + sg * 8;
      __builtin_amdgcn_global_load_lds((gld_src_t)srcA,
                                       (gld_dst_t)&Ash[(i * 256 + w * 64) * 8],
                                       16, 0, 0);
      const u16* srcB = Bw + (size_t)(n0 + row) * K + kt + sg * 8;
      __builtin_amdgcn_global_load_lds((gld_src_t)srcB,
                                       (gld_dst_t)&Bsh[(i * 256 + w * 64) * 8],
                                       16, 0, 0);
    }
    __syncthreads();
#pragma unroll
    for (int kk = 0; kk < 2; ++kk) {
      bf16x8 af[4], bfr[4];
#pragma unroll
      for (int m = 0; m < 4; ++m) {
        int r = wr * 64 + m * 16 + (lane & 15);
        int slot = (kk * 4 + (lane >> 4)) ^ (r & 7);
        af[m] = *(const bf16x8*)((const char*)Ash + r * 128 + slot * 16);
      }
#pragma unroll
      for (int n = 0; n < 4; ++n) {
        int r = wc * 64 + n * 16 + (lane & 15);
        int slot = (kk * 4 + (lane >> 4)) ^ (r & 7);
        bfr[n] = *(const bf16x8*)((const char*)Bsh + r * 128 + slot * 16);
      }
#pragma unroll
      for (int m = 0; m < 4; ++m)
#pragma unroll
        for (int n = 0; n < 4; ++n) acc[m][n] = MFMA16(af[m], bfr[n], acc[m][n]);
    }
  }

  // epilogue; C/D layout: col = lane&15, row = (lane>>4)*4 + reg
#pragma unroll
  for (int m = 0; m < 4; ++m) {
#pragma unroll
    for (int n = 0; n < 4; ++n) {
      int r0 = m0 + wr * 64 + m * 16 + ((lane >> 4) << 2);
      int col = n0 + wc * 64 + n * 16 + (lane & 15);
      if constexpr (EPI == 0) {
        int t0 = r0 & 1023;
        float4 pb = *(const float4*)(Wpos + (size_t)col * 1536 + 512 + t0);
        float pbv[4] = {pb.x, pb.y, pb.z, pb.w};
#pragma unroll
        for (int q = 0; q < 4; ++q)
          Out[(size_t)(r0 + q) * 1024 + col] = f2bf(acc[m][n][q] + pbv[q]);
      } else {
        // z==0 (Q): fold softmax scale * log2(e) so attention exp is bare exp2
        float qsc = (blockIdx.z == 0) ? 0.18033688011112042f : 1.0f;
        int hd = col >> 6, j = col & 63;
        int b = r0 >> 10;
        size_t bh = (size_t)(b * 16 + hd) * 65536;
#pragma unroll
        for (int q = 0; q < 4; ++q) {
          int t = (r0 + q) & 1023;
          // V^T (z==2): sigma^-1 within 32-kv blocks so attention's PV
          // A-fragment (k-slot p = hi*8+j) reads kv = sigma(p) contiguously
          int kv5 = t & 31;
          int tp = (t & ~31) | (((kv5 >> 2) & 3) * 8 + ((kv5 >> 4) & 1) * 4 +
                                (kv5 & 3));
          size_t idx = (blockIdx.z == 2) ? bh + (size_t)j * 1024 + tp
                                         : bh + (size_t)t * 64 + j;
          Out[idx] = f2bf(acc[m][n][q] * qsc);
        }
      }
    }
  }
}

// ---------------- attention ----------------
// One wave owns 16 q-rows (4096 waves -> 4 waves/SIMD, 2x round-6 occupancy).
// Swapped QK^T: S^T = mfma16(A=K, B=Q^T) so lane holds S^T[kv][q=lane&15] for
// kv in {hi*4+r} u {16+hi*4+r} per 32-kv tile. Softmax lane-local (bare exp2,
// Q pre-scaled). PV: O^T = mfma16(A=V^T_sigma, B=P^T) with sigma k-slot
// relabeling -> pf[j] = pe[j] (lane's own registers, no cross-lane), V A-frag
// one 16B load. Named A/B register double-buffer + memory-clobber after each
// prefetch issue so the compiler cannot sink the loads to their use (round-6
// failure mode: VGPR=76 proved buffers never live).
__global__ __launch_bounds__(256, 4) void attn(const u16* __restrict__ Q,
                                               const u16* __restrict__ K,
                                               const u16* __restrict__ Vt,
                                               float* __restrict__ out) {
  __shared__ float lbuf[4][16 * 68];
  const int tid = threadIdx.x, lane = tid & 63, w = tid >> 6;
  const int q = lane & 15, hi = lane >> 4;
  // XCD swizzle: flat%8 = xcd; 8 bh per XCD (2MB K+V resident in 4MB L2)
  const int flat = blockIdx.x;
  const int bh = (flat & 7) * 8 + ((flat >> 3) & 7);
  const int q0w = (flat >> 6) * 64 + w * 16;
  const size_t base = (size_t)bh * 65536;

  // Q B-frags: col=q, k-slot j -> dk = ks*32 + hi*8 + j
  bf16x8 qf[2];
#pragma unroll
  for (int ks = 0; ks < 2; ++ks)
    qf[ks] =
        *(const bf16x8*)(Q + base + (size_t)(q0w + q) * 64 + ks * 32 + hi * 8);

  f32x4 od[4];
#pragma unroll
  for (int d = 0; d < 4; ++d) od[d] = (f32x4){0.f, 0.f, 0.f, 0.f};
  float lsum = 0.f;

  const u16* Kp = K + base + (size_t)q * 64 + hi * 8;   // + kv*64 + ks*32
  const u16* Vp = Vt + base + (size_t)q * 1024 + hi * 8;  // + d*16*1024 + kv0

  auto loadK = [&](int kv0, bf16x8 (&kb)[4]) {
#pragma unroll
    for (int u = 0; u < 2; ++u)
#pragma unroll
      for (int ks = 0; ks < 2; ++ks)
        kb[u * 2 + ks] =
            *(const bf16x8*)(Kp + (size_t)(kv0 + u * 16) * 64 + ks * 32);
  };
  auto loadV = [&](int kv0, bf16x8 (&vb)[4]) {
#pragma unroll
    for (int d = 0; d < 4; ++d)
      vb[d] = *(const bf16x8*)(Vp + (size_t)(d * 16) * 1024 + kv0);
  };
  auto compute = [&](const bf16x8 (&kb)[4], const bf16x8 (&vb)[4]) {
    f32x4 s[2];
#pragma unroll
    for (int u = 0; u < 2; ++u) {
      s[u] = (f32x4){0.f, 0.f, 0.f, 0.f};
      s[u] = MFMA16(kb[u * 2 + 0], qf[0], s[u]);
      s[u] = MFMA16(kb[u * 2 + 1], qf[1], s[u]);
    }
    float pe[8];
#pragma unroll
    for (int r = 0; r < 4; ++r) {
      pe[r] = __builtin_exp2f(s[0][r]);
      pe[4 + r] = __builtin_exp2f(s[1][r]);
    }
    lsum += ((pe[0] + pe[1]) + (pe[2] + pe[3])) +
            ((pe[4] + pe[5]) + (pe[6] + pe[7]));
    bf16x8 pf;
#pragma unroll
    for (int j = 0; j < 8; ++j) pf[j] = (__bf16)pe[j];
#pragma unroll
    for (int d = 0; d < 4; ++d) od[d] = MFMA16(vb[d], pf, od[d]);
  };

  bf16x8 kA[4], vA[4], kB[4], vB[4];
  loadK(0, kA);
  loadV(0, vA);
  asm volatile("" ::: "memory");
  for (int kv0 = 0; kv0 < 1024; kv0 += 64) {
    loadK(kv0 + 32, kB);
    loadV(kv0 + 32, vB);
    asm volatile("" ::: "memory");
    compute(kA, vA);
    if (kv0 + 64 < 1024) {
      loadK(kv0 + 64, kA);
      loadV(kv0 + 64, vA);
      asm volatile("" ::: "memory");
    }
    compute(kB, vB);
  }

  // lanes sharing q: {q, q+16, q+32, q+48} hold disjoint kv subsets
  lsum += __shfl_xor(lsum, 16, 64);
  lsum += __shfl_xor(lsum, 32, 64);
  float ri = 1.0f / lsum;

  // O^T[dv][q] -> LDS transpose -> coalesced float4 stores
  float* lb = &lbuf[w][0];
#pragma unroll
  for (int d = 0; d < 4; ++d) {
    f32x4 v = od[d];
    *(float4*)(lb + q * 68 + d * 16 + hi * 4) =
        make_float4(v[0] * ri, v[1] * ri, v[2] * ri, v[3] * ri);
  }
  __syncthreads();
  const int b = bh >> 4, hd = bh & 15;
  {
    int row = lane >> 2, c0 = (lane & 3) * 16;
    float* op = out + ((size_t)(b * 1024 + q0w + row)) * 1024 + hd * 64 + c0;
    const float* lr = lb + row * 68 + c0;
#pragma unroll
    for (int i = 0; i < 4; ++i) {
      float4 v = *(const float4*)(lr + i * 4);
      *(float4*)(op + i * 4) = v;
    }
  }
}

// ---------------- launch ----------------

extern "C" void kernel_launch(void* const* d_in, const int* in_sizes, int n_in,
                              void* d_out, int out_size, void* d_ws,
                              size_t ws_size, hipStream_t stream) {
  const float* data = (const float*)d_in[0];
  const float* Win = (const float*)d_in[1];
  const float* Wq = (const float*)d_in[2];
  const float* Wk = (const float*)d_in[3];
  const float* Wv = (const float*)d_in[4];
  float* out = (float*)d_out;

  char* ws = (char*)d_ws;
  u16* data_b = (u16*)ws; ws += (size_t)4096 * 512 * 2;
  u16* wd_b = (u16*)ws;   ws += (size_t)1024 * 512 * 2;
  u16* wq_b = (u16*)ws;   ws += (size_t)1024 * 1024 * 2;
  u16* wk_b = (u16*)ws;   ws += (size_t)1024 * 1024 * 2;
  u16* wv_b = (u16*)ws;   ws += (size_t)1024 * 1024 * 2;
  u16* h_b = (u16*)ws;    ws += (size_t)4096 * 1024 * 2;
  u16* q_b = (u16*)ws;    ws += (size_t)4194304 * 2;  // [bh][t][64], pre-scaled
  u16* k_b = (u16*)ws;    ws += (size_t)4194304 * 2;  // [bh][t][64]
  u16* vt_b = (u16*)ws;   ws += (size_t)4194304 * 2;  // [bh][64][t] sigma-perm

  cvt_all<<<dim3(1024, 4), 256, 0, stream>>>(data, Wq, Wk, Wv, data_b, wq_b,
                                             wk_b, wv_b);
  cvt_win<<<dim3(256), 256, 0, stream>>>(Win, wd_b);
  gemm_bt<0><<<dim3(32, 8, 1), 256, 0, stream>>>(data_b, wd_b, wd_b, wd_b, Win,
                                                 h_b, h_b, h_b, 512);
  gemm_bt<1><<<dim3(32, 8, 3), 256, 0, stream>>>(h_b, wq_b, wk_b, wv_b, nullptr,
                                                 q_b, k_b, vt_b, 1024);
  attn<<<dim3(1024), 256, 0, stream>>>(q_b, k_b, vt_b, out);
}

// Round 8
// 200.383 us; speedup vs baseline: 1.2284x; 1.2284x over previous
//
#include <hip/hip_runtime.h>
#include <stdint.h>

// B=4, T=1024, DIN=512, DLIN=1024, DK=DV=1024, NH=16, dk=dv=64
// h = data @ W_in[:, :512]^T + W_in[:, 512+t]   (identity concat == column bias)
// q/k/v = h @ W^T ; per-head attention, no max-subtract needed (logits ~ +-0.5).
// Q pre-scaled by 0.125*log2(e) in the QKV GEMM epilogue -> softmax is bare exp2.
// V^T stored with kv bits 2<->3 swapped (phi involution) so PV's A-fragment
// reads are contiguous 16B and P feeds the B-operand from the lane's own regs.

typedef __bf16 bf16x8 __attribute__((ext_vector_type(8)));
typedef float f32x4 __attribute__((ext_vector_type(4)));
typedef float f32x16 __attribute__((ext_vector_type(16)));
typedef unsigned short u16;
typedef u16 u16x8 __attribute__((ext_vector_type(8)));

#define MFMA16(a, b, c) __builtin_amdgcn_mfma_f32_16x16x32_bf16(a, b, c, 0, 0, 0)
#define MFMA32(a, b, c) __builtin_amdgcn_mfma_f32_32x32x16_bf16(a, b, c, 0, 0, 0)

using gld_src_t = const __attribute__((address_space(1))) unsigned int*;
using gld_dst_t = __attribute__((address_space(3))) unsigned int*;

__device__ __forceinline__ u16 f2bf(float f) {
  uint32_t u = __builtin_bit_cast(uint32_t, f);
  uint32_t r = (u + 0x7fffu + ((u >> 16) & 1u)) >> 16;
  return (u16)r;
}

// ---------------- conversions ----------------

__global__ __launch_bounds__(256) void cvt_all(
    const float* __restrict__ data, const float* __restrict__ wq,
    const float* __restrict__ wk, const float* __restrict__ wv,
    u16* __restrict__ o_data, u16* __restrict__ o_wq,
    u16* __restrict__ o_wk, u16* __restrict__ o_wv) {
  const float* s;
  u16* o;
  int n;
  switch (blockIdx.y) {
    case 0: s = data; o = o_data; n = 4096 * 512; break;
    case 1: s = wq; o = o_wq; n = 1024 * 1024; break;
    case 2: s = wk; o = o_wk; n = 1024 * 1024; break;
    default: s = wv; o = o_wv; n = 1024 * 1024; break;
  }
  int i = (blockIdx.x * 256 + threadIdx.x) * 8;
  if (i >= n) return;
  float4 a = *(const float4*)(s + i);
  float4 b = *(const float4*)(s + i + 4);
  u16x8 v;
  v[0] = f2bf(a.x); v[1] = f2bf(a.y); v[2] = f2bf(a.z); v[3] = f2bf(a.w);
  v[4] = f2bf(b.x); v[5] = f2bf(b.y); v[6] = f2bf(b.z); v[7] = f2bf(b.w);
  *(u16x8*)(o + i) = v;
}

__global__ __launch_bounds__(256) void cvt_win(const float* __restrict__ Win,
                                               u16* __restrict__ wd) {
  int i = (blockIdx.x * 256 + threadIdx.x) * 8;  // over 1024*512
  if (i >= 1024 * 512) return;
  int row = i >> 9, col = i & 511;
  const float* s = Win + (size_t)row * 1536 + col;
  float4 a = *(const float4*)s;
  float4 b = *(const float4*)(s + 4);
  u16x8 v;
  v[0] = f2bf(a.x); v[1] = f2bf(a.y); v[2] = f2bf(a.z); v[3] = f2bf(a.w);
  v[4] = f2bf(b.x); v[5] = f2bf(b.y); v[6] = f2bf(b.z); v[7] = f2bf(b.w);
  *(u16x8*)(wd + i) = v;
}

// ---------------- GEMM: C[4096,1024] = A[4096,K] @ Bw[1024,K]^T ----------------

template <int EPI>
__global__ __launch_bounds__(256) void gemm_bt(
    const u16* __restrict__ A, const u16* __restrict__ B0,
    const u16* __restrict__ B1, const u16* __restrict__ B2,
    const float* __restrict__ Wpos, u16* __restrict__ O0,
    u16* __restrict__ O1, u16* __restrict__ O2, int K) {
  __shared__ u16 Ash[128 * 64];
  __shared__ u16 Bsh[128 * 64];
  const int tid = threadIdx.x;
  const int lane = tid & 63;
  const int w = tid >> 6;
  const int wr = w >> 1, wc = w & 1;
  const int m0 = blockIdx.x * 128, n0 = blockIdx.y * 128;

  const u16* Bw;
  u16* Out;
  if constexpr (EPI == 0) {
    Bw = B0; Out = O0;
  } else {
    int z = blockIdx.z;
    Bw = (z == 0) ? B0 : (z == 1) ? B1 : B2;
    Out = (z == 0) ? O0 : (z == 1) ? O1 : O2;
  }

  f32x4 acc[4][4];
#pragma unroll
  for (int m = 0; m < 4; ++m)
#pragma unroll
    for (int n = 0; n < 4; ++n) acc[m][n] = (f32x4){0.f, 0.f, 0.f, 0.f};

  for (int kt = 0; kt < K; kt += 64) {
    __syncthreads();
#pragma unroll
    for (int i = 0; i < 4; ++i) {
      int c = i * 256 + tid;
      int row = c >> 3;
      int sg = (c & 7) ^ (row & 7);
      const u16* srcA = A + (size_t)(m0 + row) * K + kt + sg * 8;
      __builtin_amdgcn_global_load_lds((gld_src_t)srcA,
                                       (gld_dst_t)&Ash[(i * 256 + w * 64) * 8],
                                       16, 0, 0);
      const u16* srcB = Bw + (size_t)(n0 + row) * K + kt + sg * 8;
      __builtin_amdgcn_global_load_lds((gld_src_t)srcB,
                                       (gld_dst_t)&Bsh[(i * 256 + w * 64) * 8],
                                       16, 0, 0);
    }
    __syncthreads();
#pragma unroll
    for (int kk = 0; kk < 2; ++kk) {
      bf16x8 af[4], bfr[4];
#pragma unroll
      for (int m = 0; m < 4; ++m) {
        int r = wr * 64 + m * 16 + (lane & 15);
        int slot = (kk * 4 + (lane >> 4)) ^ (r & 7);
        af[m] = *(const bf16x8*)((const char*)Ash + r * 128 + slot * 16);
      }
#pragma unroll
      for (int n = 0; n < 4; ++n) {
        int r = wc * 64 + n * 16 + (lane & 15);
        int slot = (kk * 4 + (lane >> 4)) ^ (r & 7);
        bfr[n] = *(const bf16x8*)((const char*)Bsh + r * 128 + slot * 16);
      }
#pragma unroll
      for (int m = 0; m < 4; ++m)
#pragma unroll
        for (int n = 0; n < 4; ++n) acc[m][n] = MFMA16(af[m], bfr[n], acc[m][n]);
    }
  }

  // epilogue; C/D layout: col = lane&15, row = (lane>>4)*4 + reg
#pragma unroll
  for (int m = 0; m < 4; ++m) {
#pragma unroll
    for (int n = 0; n < 4; ++n) {
      int r0 = m0 + wr * 64 + m * 16 + ((lane >> 4) << 2);
      int col = n0 + wc * 64 + n * 16 + (lane & 15);
      if constexpr (EPI == 0) {
        int t0 = r0 & 1023;
        float4 pb = *(const float4*)(Wpos + (size_t)col * 1536 + 512 + t0);
        float pbv[4] = {pb.x, pb.y, pb.z, pb.w};
#pragma unroll
        for (int q = 0; q < 4; ++q)
          Out[(size_t)(r0 + q) * 1024 + col] = f2bf(acc[m][n][q] + pbv[q]);
      } else {
        // z==0 (Q): fold softmax scale * log2(e) so attention exp is bare exp2
        float qsc = (blockIdx.z == 0) ? 0.18033688011112042f : 1.0f;
        int hd = col >> 6, j = col & 63;
        int b = r0 >> 10;
        size_t bh = (size_t)(b * 16 + hd) * 65536;
#pragma unroll
        for (int q = 0; q < 4; ++q) {
          int t = (r0 + q) & 1023;
          // V^T (z==2): swap kv bits 2<->3 (phi involution) for 16B PV loads
          int tp = (t & ~12) | ((t & 4) << 1) | ((t & 8) >> 1);
          size_t idx = (blockIdx.z == 2) ? bh + (size_t)j * 1024 + tp
                                         : bh + (size_t)t * 64 + j;
          Out[idx] = f2bf(acc[m][n][q] * qsc);
        }
      }
    }
  }
}

// ---------------- attention (LDS-staged, 1 barrier per 64-kv tile) ----------
// 4 waves x 32 q-rows = 128 q per block; grid 8 qtiles x 64 bh = 512 blocks.
// Round-6 verified algebra: S^T = mfma32(A=K, B=Q) -> lane holds
// S^T[kv][q=lane&31], kv = u*32 + (r&3)+8*(r>>2)+4*hi. Softmax lane-local
// (bare exp2). PV: pf[j] = pe[8s+j] from own regs; V^T phi-stored so the
// A-fragment is one 16B LDS read. K/V^T staged to double-buffered LDS
// (rows padded to 136B -> uniform bank load, no excess conflict). T14 split:
// global loads for tile t+1 issue BEFORE compute(t); ds_write + ONE barrier
// after. The barrier pins the schedule (r6/r7 lesson: clobbers don't).
__global__ __launch_bounds__(256, 2) void attn(const u16* __restrict__ Q,
                                               const u16* __restrict__ K,
                                               const u16* __restrict__ Vt,
                                               float* __restrict__ out) {
  __shared__ __align__(16) u16 smem[2 * 64 * 68 * 2];  // K[2][64][68] V[2][64][68]
  u16* const Klds = smem;
  u16* const Vlds = smem + 2 * 64 * 68;
  const int tid = threadIdx.x, lane = tid & 63, w = tid >> 6;
  const int q = lane & 31, hi = lane >> 5;
  // XCD swizzle: flat%8 = xcd; 8 bh per XCD (2MB K+V resident in 4MB L2)
  const int flat = blockIdx.x;
  const int bh = (flat & 7) * 8 + ((flat >> 3) & 7);
  const int q0 = (flat >> 6) * 128 + w * 32;
  const size_t base = (size_t)bh * 65536;

  // Q B-frags: col=q, k = ks*16 + hi*8 + j
  bf16x8 qf[4];
#pragma unroll
  for (int ks = 0; ks < 4; ++ks)
    qf[ks] = *(const bf16x8*)(Q + base + (size_t)(q0 + q) * 64 + ks * 16 + hi * 8);

  f32x16 od[2];
#pragma unroll
  for (int r = 0; r < 16; ++r) {
    od[0][r] = 0.f;
    od[1][r] = 0.f;
  }
  float lsum = 0.f;

  const u16* Kg = K + base;
  const u16* Vg = Vt + base;
  const int srow = tid >> 3, sch = tid & 7;  // staging: 64 rows x 8 chunks, 2 it

  bf16x8 kst[2], vst[2];
  auto gload = [&](int kv0) {
    kst[0] = *(const bf16x8*)(Kg + (size_t)(kv0 + srow) * 64 + sch * 8);
    kst[1] = *(const bf16x8*)(Kg + (size_t)(kv0 + srow + 32) * 64 + sch * 8);
    vst[0] = *(const bf16x8*)(Vg + (size_t)srow * 1024 + kv0 + sch * 8);
    vst[1] = *(const bf16x8*)(Vg + (size_t)(srow + 32) * 1024 + kv0 + sch * 8);
  };
  auto swrite = [&](int buf) {
    u16* kd = Klds + buf * (64 * 68);
    u16* vd = Vlds + buf * (64 * 68);
    *(bf16x8*)(kd + srow * 68 + sch * 8) = kst[0];
    *(bf16x8*)(kd + (srow + 32) * 68 + sch * 8) = kst[1];
    *(bf16x8*)(vd + srow * 68 + sch * 8) = vst[0];
    *(bf16x8*)(vd + (srow + 32) * 68 + sch * 8) = vst[1];
  };
  auto compute = [&](int buf) {
    const u16* kb = Klds + buf * (64 * 68);
    const u16* vb = Vlds + buf * (64 * 68);
#pragma unroll
    for (int u = 0; u < 2; ++u) {
      f32x16 st;
#pragma unroll
      for (int r = 0; r < 16; ++r) st[r] = 0.f;
#pragma unroll
      for (int ks = 0; ks < 4; ++ks) {
        bf16x8 kf =
            *(const bf16x8*)(kb + (u * 32 + q) * 68 + ks * 16 + hi * 8);
        st = MFMA32(kf, qf[ks], st);
      }
      float pe[16];
#pragma unroll
      for (int r = 0; r < 16; ++r) pe[r] = __builtin_exp2f(st[r]);
      {
        float t0 = (pe[0] + pe[1]) + (pe[2] + pe[3]);
        float t1 = (pe[4] + pe[5]) + (pe[6] + pe[7]);
        float t2 = (pe[8] + pe[9]) + (pe[10] + pe[11]);
        float t3 = (pe[12] + pe[13]) + (pe[14] + pe[15]);
        lsum += (t0 + t1) + (t2 + t3);
      }
#pragma unroll
      for (int s = 0; s < 2; ++s) {
        bf16x8 pf;
#pragma unroll
        for (int j = 0; j < 8; ++j) pf[j] = (__bf16)pe[8 * s + j];
#pragma unroll
        for (int d = 0; d < 2; ++d) {
          bf16x8 vf = *(const bf16x8*)(vb + (q + 32 * d) * 68 + u * 32 +
                                       s * 16 + hi * 8);
          od[d] = MFMA32(vf, pf, od[d]);
        }
      }
    }
  };

  gload(0);
  swrite(0);
  __syncthreads();
  int buf = 0;
  for (int t = 0; t < 16; ++t) {
    if (t < 15) {
      gload((t + 1) * 64);
      __builtin_amdgcn_sched_barrier(0);  // loads may not sink past this
    }
    compute(buf);
    if (t < 15) {
      swrite(buf ^ 1);  // compiler inserts vmcnt before first dependent write
      __syncthreads();
      buf ^= 1;
    }
  }

  // lanes (l, l+32) share q and hold disjoint kv subsets
  lsum += __shfl_xor(lsum, 32, 64);
  float ri = 1.0f / lsum;

  __syncthreads();  // all waves done with K/V LDS before aliasing as lbuf
  float* lb = (float*)smem + w * (32 * 66);
#pragma unroll
  for (int d = 0; d < 2; ++d)
#pragma unroll
    for (int rr = 0; rr < 16; rr += 2) {
      int dv = 32 * d + (rr & 3) + 8 * (rr >> 2) + 4 * hi;
      *(float2*)(lb + q * 66 + dv) =
          make_float2(od[d][rr] * ri, od[d][rr + 1] * ri);
    }
  __syncthreads();
  const int b = bh >> 4, hd = bh & 15;
#pragma unroll
  for (int i = 0; i < 8; ++i) {
    int row = i * 4 + (lane >> 4);
    const float* lr = lb + row * 66 + (lane & 15) * 4;
    float2 x0 = *(const float2*)lr;
    float2 x1 = *(const float2*)(lr + 2);
    float4 v = make_float4(x0.x, x0.y, x1.x, x1.y);
    *(float4*)(out + ((size_t)(b * 1024 + q0 + row)) * 1024 + hd * 64 +
               (lane & 15) * 4) = v;
  }
}

// ---------------- launch ----------------

extern "C" void kernel_launch(void* const* d_in, const int* in_sizes, int n_in,
                              void* d_out, int out_size, void* d_ws,
                              size_t ws_size, hipStream_t stream) {
  const float* data = (const float*)d_in[0];
  const float* Win = (const float*)d_in[1];
  const float* Wq = (const float*)d_in[2];
  const float* Wk = (const float*)d_in[3];
  const float* Wv = (const float*)d_in[4];
  float* out = (float*)d_out;

  char* ws = (char*)d_ws;
  u16* data_b = (u16*)ws; ws += (size_t)4096 * 512 * 2;
  u16* wd_b = (u16*)ws;   ws += (size_t)1024 * 512 * 2;
  u16* wq_b = (u16*)ws;   ws += (size_t)1024 * 1024 * 2;
  u16* wk_b = (u16*)ws;   ws += (size_t)1024 * 1024 * 2;
  u16* wv_b = (u16*)ws;   ws += (size_t)1024 * 1024 * 2;
  u16* h_b = (u16*)ws;    ws += (size_t)4096 * 1024 * 2;
  u16* q_b = (u16*)ws;    ws += (size_t)4194304 * 2;  // [bh][t][64], pre-scaled
  u16* k_b = (u16*)ws;    ws += (size_t)4194304 * 2;  // [bh][t][64]
  u16* vt_b = (u16*)ws;   ws += (size_t)4194304 * 2;  // [bh][64][t] phi-swizzled

  cvt_all<<<dim3(1024, 4), 256, 0, stream>>>(data, Wq, Wk, Wv, data_b, wq_b,
                                             wk_b, wv_b);
  cvt_win<<<dim3(256), 256, 0, stream>>>(Win, wd_b);
  gemm_bt<0><<<dim3(32, 8, 1), 256, 0, stream>>>(data_b, wd_b, wd_b, wd_b, Win,
                                                 h_b, h_b, h_b, 512);
  gemm_bt<1><<<dim3(32, 8, 3), 256, 0, stream>>>(h_b, wq_b, wk_b, wv_b, nullptr,
                                                 q_b, k_b, vt_b, 1024);
  attn<<<dim3(512), 256, 0, stream>>>(q_b, k_b, vt_b, out);
}